// Round 8
// baseline (1161.314 us; speedup 1.0000x reference)
//
#include <hip/hip_runtime.h>
#include <math.h>

// Problem constants (B=8, T=256 -> 2048 independent (b,t) pipelines)
// Structure: ONE WAVE (64 threads) per pipeline; no inter-wave barriers.
// R8: __launch_bounds__(64,1) (no 256-total arch/acc split -> no scratch spill),
// pairwise B loads (B live 32->16), 2 ng-passes of 8 n-tiles, it-loop not unrolled.
#define NBT 2048

typedef __attribute__((ext_vector_type(8))) short short8;     // 8 bf16 (4 VGPRs)
typedef __attribute__((ext_vector_type(4))) float floatx4;    // MFMA C/D

struct SM {
  alignas(16) float xp[240];      // zero-padded encoder input (nonzero in [80,160))
  alignas(16) unsigned xhl[256];  // packed bf16: hi | lo<<16, zero-padded to 256
  alignas(16) float hsq[256];     // h^2 for top-64 ranking
  alignas(16) float yres[80];
  alignas(16) float beL[256];     // encoder bias staged in LDS
  alignas(16) float spad[240];    // padded buffer for sim windows
  alignas(16) float dval[64];     // compacted selected hidden values (ascending idx)
  alignas(16) int   dlist[64];    // compacted selected hidden indices (ascending)
  float xres[80];
  float yal[80];
  float xele[80];
  float decsrc[80];
  float zb[80];
  float energy[96];               // 81 valid + pad (6 m-tiles of 16)
  float mp_self[256];
  float mp_src[256];
  float ext[160];
  unsigned char smask[80];
  int smask_t;
};

// ---- wave-level primitives (64 lanes, butterfly -> all lanes hold result) ----
__device__ __forceinline__ float waveSum(float v){
  #pragma unroll
  for (int off = 32; off > 0; off >>= 1) v += __shfl_xor(v, off, 64);
  return v;
}
__device__ __forceinline__ int waveSumI(int v){
  #pragma unroll
  for (int off = 32; off > 0; off >>= 1) v += __shfl_xor(v, off, 64);
  return v;
}
__device__ __forceinline__ float waveMax(float v){
  #pragma unroll
  for (int off = 32; off > 0; off >>= 1) v = fmaxf(v, __shfl_xor(v, off, 64));
  return v;
}
// argmax with JAX tie rule: first (lowest index) max wins; symmetric butterfly
__device__ __forceinline__ int waveArgMax(float v, int idx){
  #pragma unroll
  for (int off = 32; off > 0; off >>= 1){
    float ov = __shfl_xor(v,   off, 64);
    int   oi = __shfl_xor(idx, off, 64);
    if (ov > v || (ov == v && oi < idx)){ v = ov; idx = oi; }
  }
  return idx;
}

// top-64 membership via rank for this lane's 4 hidden units (j = lane + 64q).
// rank = #{i: v_i > v_j} + #{i<j: v_i == v_j}; selected iff rank < 64.
// hsq[i4] reads are wave-uniform -> LDS broadcast, conflict-free.
__device__ __forceinline__ void rankTop64w(SM& sm, const float vsq[4], int lane, int sel[4]){
  int cnt[4] = {0,0,0,0};
  const float4* q4 = (const float4*)sm.hsq;
  #pragma unroll 4
  for (int i4 = 0; i4 < 64; i4++){
    float4 o = q4[i4];
    int ib = i4 * 4;
    #pragma unroll
    for (int q = 0; q < 4; q++){
      int j = lane + 64 * q;
      cnt[q] += (o.x > vsq[q] || (o.x == vsq[q] && (ib + 0) < j)) ? 1 : 0;
      cnt[q] += (o.y > vsq[q] || (o.y == vsq[q] && (ib + 1) < j)) ? 1 : 0;
      cnt[q] += (o.z > vsq[q] || (o.z == vsq[q] && (ib + 2) < j)) ? 1 : 0;
      cnt[q] += (o.w > vsq[q] || (o.w == vsq[q] && (ib + 3) < j)) ? 1 : 0;
    }
  }
  #pragma unroll
  for (int q = 0; q < 4; q++) sel[q] = (cnt[q] < 64) ? 1 : 0;
}

// Compact the exactly-64 selected (index,value) pairs into ascending-index LDS
// lists via wave ballots. Ascending order => decode accumulation order matches
// the reference (skipped entries are exact zeros: fmaf(0,w,a)==a bit-exactly).
__device__ __forceinline__ void compactSel(SM& sm, const int sel[4], const float val[4], int lane){
  unsigned long long mq[4];
  #pragma unroll
  for (int q = 0; q < 4; q++) mq[q] = __ballot(sel[q] != 0);
  int base1 = __popcll(mq[0]);
  int base2 = base1 + __popcll(mq[1]);
  int base3 = base2 + __popcll(mq[2]);
  int base[4] = {0, base1, base2, base3};
  unsigned long long below = (lane == 0) ? 0ull : ((~0ull) >> (64 - lane));
  #pragma unroll
  for (int q = 0; q < 4; q++){
    if (sel[q]){
      int pos = base[q] + (int)__popcll(mq[q] & below);
      sm.dlist[pos] = lane + 64 * q;
      sm.dval[pos]  = val[q];
    }
  }
}

// sim_argmax: cosine sim over 159 shifts of src vs yres; each lane owns shifts
// {lane, lane+64, lane+128}. Per-candidate fmaf chain order preserved.
__device__ __forceinline__ int simArgmax(SM& sm, const float* src, float* yal_out){
  int lane = threadIdx.x;
  __syncthreads();
  for (int i = lane; i < 240; i += 64)
    sm.spad[i] = (i >= 79 && i < 159) ? src[i - 79] : 0.f;
  __syncthreads();
  float yv2 = 0.f;
  for (int w = lane; w < 80; w += 64){ float yv = sm.yres[w]; yv2 = fmaf(yv, yv, yv2); }
  float nys = sqrtf(waveSum(yv2));

  int   sidx[3]; int svalid[3];
  #pragma unroll
  for (int c = 0; c < 3; c++){
    int s = lane + 64 * c;
    svalid[c] = (s < 159);
    sidx[c] = svalid[c] ? s : 0;      // clamp to keep reads in-bounds
  }
  float num[3] = {0.f,0.f,0.f}, nx[3] = {0.f,0.f,0.f};
  const float4* y4p = (const float4*)sm.yres;
  for (int w4 = 0; w4 < 20; w4++){
    float4 yy = y4p[w4];
    int w = w4 * 4;
    #pragma unroll
    for (int c = 0; c < 3; c++){
      float xa0 = sm.spad[sidx[c] + w + 0];
      float xa1 = sm.spad[sidx[c] + w + 1];
      float xa2 = sm.spad[sidx[c] + w + 2];
      float xa3 = sm.spad[sidx[c] + w + 3];
      num[c] = fmaf(xa0, yy.x, num[c]); nx[c] = fmaf(xa0, xa0, nx[c]);
      num[c] = fmaf(xa1, yy.y, num[c]); nx[c] = fmaf(xa1, xa1, nx[c]);
      num[c] = fmaf(xa2, yy.z, num[c]); nx[c] = fmaf(xa2, xa2, nx[c]);
      num[c] = fmaf(xa3, yy.w, num[c]); nx[c] = fmaf(xa3, xa3, nx[c]);
    }
  }
  float bv = -INFINITY; int bi = 0;
  #pragma unroll
  for (int c = 0; c < 3; c++){          // ascending index: strict > keeps lowest idx on ties
    if (svalid[c]){
      float simv = num[c] / (sqrtf(nx[c]) * nys + 1e-6f);
      if (simv > bv){ bv = simv; bi = lane + 64 * c; }
    }
  }
  int th = waveArgMax(bv, bi);
  for (int i = lane; i < 80; i += 64) yal_out[i] = sm.spad[th + i];
  __syncthreads();
  return th;
}

// One branch: MFMA energy (split bf16, kt-trimmed to nonzero support — bit-safe),
// argmax, exact fp32 row recompute, hsr, sparse decode, masked loss.
template<int USE_WS>
__device__ __forceinline__ void branchCompute(
    SM& sm, const float* __restrict__ We,
    const short8* __restrict__ wsBh, const short8* __restrict__ wsBl,
    const float* __restrict__ Wdec, const float* __restrict__ bdec,
    const float* enc_in, float* mask, const float* target,
    float* dec_out, int theta, bool first, float& lossAcc)
{
  int lane = threadIdx.x;
  int quad = lane >> 4, l15 = lane & 15;
  __syncthreads();
  for (int i = lane; i < 256; i += 64){
    float v = (i >= 80 && i < 160) ? enc_in[i - 80] : 0.f;
    if (i < 240) sm.xp[i] = v;
    unsigned bits = __float_as_uint(v);
    unsigned hi = bits >> 16;
    float hif = __uint_as_float(hi << 16);
    unsigned lo = __float_as_uint(v - hif) >> 16;
    sm.xhl[i] = hi | (lo << 16);
  }
  __syncthreads();

  const floatx4 zero4 = {0.f, 0.f, 0.f, 0.f};

  #pragma unroll 1
  for (int mh = 0; mh < 3; mh++){        // 3 m-passes x 2 m-tiles
    int ktlo = (mh == 0) ? 1 : 0;        // nonzero-support kt range for these m rows
    int kthi = 5 - mh;
    #pragma unroll 1
    for (int ng = 0; ng < 2; ng++){      // 2 n-passes x 8 n-tiles; acc[2][8]=64 regs
      floatx4 acc[2][8];
      #pragma unroll
      for (int m2 = 0; m2 < 2; m2++)
        #pragma unroll
        for (int nt = 0; nt < 8; nt++) acc[m2][nt] = zero4;

      #pragma unroll
      for (int kt = 0; kt < 5; kt++){
        if (kt < ktlo || kt >= kthi) continue;   // wave-uniform scalar skip; removed
                                                 // products are exactly 0 -> bit-safe
        // A fragments for this kt (built once per (ng,kt))
        short8 Ah[2], Al[2];
        #pragma unroll
        for (int m2 = 0; m2 < 2; m2++){
          int mt = mh * 2 + m2;
          int base = mt * 16 + l15 + kt * 32 + quad * 8;
          short8 ah, al;
          #pragma unroll
          for (int j = 0; j < 8; j++){
            unsigned u = sm.xhl[base + j];
            ah[j] = (short)(u & 0xffffu);
            al[j] = (short)(u >> 16);
          }
          Ah[m2] = ah; Al[m2] = al;
        }
        // B tiles pairwise: only 2 (hi,lo) tile pairs live at once (16 VGPRs)
        #pragma unroll
        for (int ntp = 0; ntp < 4; ntp++){
          short8 Bh0, Bl0, Bh1, Bl1;
          int nt0 = ng * 8 + ntp * 2;
          if (USE_WS){
            int t0 = (kt * 16 + nt0) * 64 + lane;
            Bh0 = wsBh[t0];       Bl0 = wsBl[t0];
            Bh1 = wsBh[t0 + 64];  Bl1 = wsBl[t0 + 64];
          } else {
            int k0 = kt * 32 + quad * 8;
            #pragma unroll
            for (int half = 0; half < 2; half++){
              short8 bh, bl;
              int n = (nt0 + half) * 16 + l15;
              #pragma unroll
              for (int j = 0; j < 8; j++){
                float v = We[(k0 + j) * 256 + n];
                unsigned bits = __float_as_uint(v);
                unsigned hi = bits >> 16;
                float hif = __uint_as_float(hi << 16);
                unsigned lo = __float_as_uint(v - hif) >> 16;
                bh[j] = (short)hi; bl[j] = (short)lo;
              }
              if (half == 0){ Bh0 = bh; Bl0 = bl; } else { Bh1 = bh; Bl1 = bl; }
            }
          }
          #pragma unroll
          for (int m2 = 0; m2 < 2; m2++){
            int a0 = ntp * 2, a1 = ntp * 2 + 1;
            acc[m2][a0] = __builtin_amdgcn_mfma_f32_16x16x32_bf16(Ah[m2], Bh0, acc[m2][a0], 0, 0, 0);
            acc[m2][a0] = __builtin_amdgcn_mfma_f32_16x16x32_bf16(Al[m2], Bh0, acc[m2][a0], 0, 0, 0);
            acc[m2][a0] = __builtin_amdgcn_mfma_f32_16x16x32_bf16(Ah[m2], Bl0, acc[m2][a0], 0, 0, 0);
            acc[m2][a1] = __builtin_amdgcn_mfma_f32_16x16x32_bf16(Ah[m2], Bh1, acc[m2][a1], 0, 0, 0);
            acc[m2][a1] = __builtin_amdgcn_mfma_f32_16x16x32_bf16(Al[m2], Bh1, acc[m2][a1], 0, 0, 0);
            acc[m2][a1] = __builtin_amdgcn_mfma_f32_16x16x32_bf16(Ah[m2], Bl1, acc[m2][a1], 0, 0, 0);
          }
        }
      }

      // epilogue: add bias, square, reduce over this pass's 128 columns (l15 butterfly)
      float bn[8];
      #pragma unroll
      for (int nt = 0; nt < 8; nt++) bn[nt] = sm.beL[(ng * 8 + nt) * 16 + l15];
      #pragma unroll
      for (int m2 = 0; m2 < 2; m2++){
        int mt = mh * 2 + m2;
        float er[4];
        #pragma unroll
        for (int r = 0; r < 4; r++){
          float s_ = 0.f;
          #pragma unroll
          for (int nt = 0; nt < 8; nt++){
            float hvv = acc[m2][nt][r] + bn[nt];
            s_ = fmaf(hvv, hvv, s_);
          }
          er[r] = s_;
        }
        #pragma unroll
        for (int x2 = 1; x2 < 16; x2 <<= 1){
          #pragma unroll
          for (int r = 0; r < 4; r++) er[r] += __shfl_xor(er[r], x2, 64);
        }
        if (l15 == 0){
          #pragma unroll
          for (int r = 0; r < 4; r++){
            int ei = mt * 16 + quad * 4 + r;
            sm.energy[ei] = (ng == 0) ? er[r] : (sm.energy[ei] + er[r]);
          }
        }
      }
      __syncthreads();   // waitcnt fence; pins pass boundaries (code-size/pressure guard)
    }
  }

  // argmax over 81 energies (padded rows >80 contain garbage correlations — mask them)
  float bv = sm.energy[lane]; int bi = lane;
  {
    int s2 = lane + 64;
    if (s2 < 81){
      float v2 = sm.energy[s2];
      if (v2 > bv){ bv = v2; bi = s2; }   // ascending index: ties keep lower
    }
  }
  int ind = waveArgMax(bv, bi);

  // recompute selected row h[ind, j] EXACTLY in fp32 for this lane's 4 js
  int roff = 80 - ind;
  float hv[4];
  #pragma unroll
  for (int q = 0; q < 4; q++) hv[q] = sm.beL[lane + 64 * q];
  #pragma unroll 4
  for (int w2 = 0; w2 < 80; w2++){
    float xv = sm.xp[80 + w2];
    const float* row = We + (w2 + roff) * 256;
    #pragma unroll
    for (int q = 0; q < 4; q++) hv[q] = fmaf(xv, row[lane + 64 * q], hv[q]);
  }

  // hsr (per lane's 4 js)
  float vsq[4];
  #pragma unroll
  for (int q = 0; q < 4; q++){ vsq[q] = hv[q] * hv[q]; sm.hsq[lane + 64 * q] = vsq[q]; }
  __syncthreads();
  int sel1[4];
  rankTop64w(sm, vsq, lane, sel1);
  float mpv[4];
  #pragma unroll
  for (int q = 0; q < 4; q++) mpv[q] = mask[lane + 64 * q];
  if (first){
    #pragma unroll
    for (int q = 0; q < 4; q++)
      mask[lane + 64 * q] = (float)sel1[q];
    compactSel(sm, sel1, hv, lane);
  } else {
    int st = sm.smask_t;
    float h2[4];
    #pragma unroll
    for (int q = 0; q < 4; q++){
      float interv = mpv[q] * (float)sel1[q];
      if (interv > 0.f && !st){
        float dd = hv[q] - (1.f - interv);
        lossAcc += dd * dd;
      }
      h2[q] = (mpv[q] > 0.f) ? 0.f : hv[q];
    }
    __syncthreads();               // rank1 readers done before hsq rewrite
    float vsq2[4];
    #pragma unroll
    for (int q = 0; q < 4; q++){ vsq2[q] = h2[q] * h2[q]; sm.hsq[lane + 64 * q] = vsq2[q]; }
    __syncthreads();
    int sel2[4];
    rankTop64w(sm, vsq2, lane, sel2);
    #pragma unroll
    for (int q = 0; q < 4; q++)
      mask[lane + 64 * q] = mpv[q] + (float)sel2[q];
    compactSel(sm, sel2, h2, lane);
  }
  __syncthreads();                 // compact list ready

  // sparse decode over the exactly-64 selected rows (ascending idx => bit-exact):
  // ext[d] = bdec[d] + sum_{sel h asc} val_h * Wdec[h*160+d]; lane owns d, d+64, d+128
  {
    int dc = 128 + (lane & 31);    // clamped third output (discarded for lane>=32)
    float a0 = bdec[lane], a1 = bdec[lane + 64], a2 = bdec[dc];
    #pragma unroll 8
    for (int i = 0; i < 64; i++){
      int idx = sm.dlist[i];       // wave-uniform broadcast
      float hval = sm.dval[i];
      const float* r = Wdec + idx * 160;
      a0 = fmaf(hval, r[lane], a0);
      a1 = fmaf(hval, r[lane + 64], a1);
      a2 = fmaf(hval, r[dc], a2);
    }
    sm.ext[lane] = a0;
    sm.ext[lane + 64] = a1;
    if (lane < 32) sm.ext[128 + lane] = a2;
  }
  __syncthreads();

  float mv = fabsf((float)(theta - 79));
  bool gate = (mv > 40.0f);        // ETH
  for (int d = lane; d < 80; d += 64){
    float dec = sm.ext[ind + d];
    dec_out[d] = dec;              // residual update uses decoded output regardless of gates
    float diff = dec - target[d];
    float l = (gate || sm.smask[d]) ? 0.f : diff * diff;
    lossAcc += l / (mv + 1.0f);
  }
  __syncthreads();
}

__global__ void __launch_bounds__(64) zero_out_kernel(float* out){
  if (threadIdx.x == 0) out[0] = 0.f;
}

// Pre-repack We into MFMA B-fragment layout (bf16 hi and lo), one 16B frag per lane per tile.
__global__ void __launch_bounds__(64) prep_we_kernel(
    const float* __restrict__ We, short8* __restrict__ bh, short8* __restrict__ bl){
  int tile = blockIdx.x;
  int lane = threadIdx.x;
  int kt = tile >> 4, nt = tile & 15;
  int k0 = kt * 32 + (lane >> 4) * 8;
  int n  = nt * 16 + (lane & 15);
  short8 h, l;
  #pragma unroll
  for (int j = 0; j < 8; j++){
    float v = We[(k0 + j) * 256 + n];
    unsigned bits = __float_as_uint(v);
    unsigned hi = bits >> 16;
    float hif = __uint_as_float(hi << 16);
    unsigned lo = __float_as_uint(v - hif) >> 16;
    h[j] = (short)hi; l[j] = (short)lo;
  }
  bh[tile * 64 + lane] = h;
  bl[tile * 64 + lane] = l;
}

template<int USE_WS>
__global__ void __launch_bounds__(64, 1) net_kernel(
    const float* __restrict__ x,  const float* __restrict__ y,
    const float* __restrict__ We, const float* __restrict__ be,
    const float* __restrict__ Wd, const float* __restrict__ bd,
    const float* __restrict__ Wds,const float* __restrict__ bds,
    const short8* __restrict__ wsBh, const short8* __restrict__ wsBl,
    float* out)
{
  __shared__ SM sm;
  int lane = threadIdx.x;
  int bt  = blockIdx.x;
  const float* xin = x + bt * 80;
  const float* yin = y + bt * 80;

  for (int i = lane; i < 80; i += 64){
    sm.xres[i] = xin[i];
    float yv = yin[i];
    sm.yres[i] = yv;
    sm.smask[i] = (yv == 0.f) ? 1 : 0;   // seq_mask from ORIGINAL y
  }
  for (int i = lane; i < 256; i += 64){
    sm.mp_self[i] = 0.f;
    sm.mp_src[i]  = 0.f;
    sm.beL[i] = be[i];
  }
  __syncthreads();
  {
    int c = 0;
    for (int i = lane; i < 80; i += 64) c += (int)sm.smask[i];
    int total = waveSumI(c);
    if (lane == 0) sm.smask_t = (total == 80) ? 1 : 0;
  }
  __syncthreads();

  float lossAcc = 0.f;

  #pragma unroll 1
  for (int it = 0; it < 4; it++){
    bool first = (it == 0);

    // --- align x_res to y_res ---
    int th1 = simArgmax(sm, sm.xres, sm.yal);

    // --- attention softmax(y_al * y_res) and z = y_al * attn ---
    {
      float p0 = sm.yal[lane] * sm.yres[lane];
      float p1 = (lane < 16) ? sm.yal[64 + lane] * sm.yres[64 + lane] : -INFINITY;
      float mx = waveMax(fmaxf(p0, p1));
      float e0 = expf(p0 - mx);
      float e1 = (lane < 16) ? expf(p1 - mx) : 0.f;
      float ssum = waveSum(e0 + e1);
      sm.zb[lane] = sm.yal[lane] * (e0 / ssum);
      if (lane < 16) sm.zb[64 + lane] = sm.yal[64 + lane] * (e1 / ssum);
    }
    __syncthreads();

    // --- reverse shift: x_ele[d] = z[d + 79 - theta] ---
    for (int d = lane; d < 80; d += 64){
      int q = d + 79 - th1;
      sm.xele[d] = (q >= 0 && q < 80) ? sm.zb[q] : 0.f;
    }

    // --- self branch ---
    branchCompute<USE_WS>(sm, We, wsBh, wsBl, Wds, bds,
                          sm.xele, sm.mp_self, sm.xres, sm.xele, th1, first, lossAcc);

    // --- re-align decoded x_ele to y_res ---
    int th2 = simArgmax(sm, sm.xele, sm.yal);

    // --- src branch ---
    branchCompute<USE_WS>(sm, We, wsBh, wsBl, Wd, bd,
                          sm.yal, sm.mp_src, sm.yres, sm.decsrc, th2, first, lossAcc);

    // --- residual updates ---
    __syncthreads();
    for (int d = lane; d < 80; d += 64){
      sm.xres[d] -= sm.xele[d];
      sm.yres[d] -= sm.decsrc[d];
    }
    __syncthreads();
  }

  float total = waveSum(lossAcc);
  if (lane == 0) atomicAdd(out, total * 0.25f);   // mean over 4 iterations
}

extern "C" void kernel_launch(void* const* d_in, const int* in_sizes, int n_in,
                              void* d_out, int out_size, void* d_ws, size_t ws_size,
                              hipStream_t stream) {
  const float* x   = (const float*)d_in[0];
  const float* y   = (const float*)d_in[1];
  const float* We  = (const float*)d_in[2];
  const float* be  = (const float*)d_in[3];
  const float* Wd  = (const float*)d_in[4];
  const float* bd  = (const float*)d_in[5];
  const float* Wds = (const float*)d_in[6];
  const float* bds = (const float*)d_in[7];
  float* out = (float*)d_out;

  // We-fragment repack buffers: 80 tiles x 64 lanes x 16B each for hi and lo
  const size_t fragCount = 80 * 64;                     // short8 elements per buffer
  const size_t fragBytes = fragCount * sizeof(short8);  // 81920 B
  int use_ws = (ws_size >= 2 * fragBytes) ? 1 : 0;
  short8* wsBh = (short8*)d_ws;
  short8* wsBl = wsBh + fragCount;

  hipLaunchKernelGGL(zero_out_kernel, dim3(1), dim3(64), 0, stream, out);
  if (use_ws){
    hipLaunchKernelGGL(prep_we_kernel, dim3(80), dim3(64), 0, stream, We, wsBh, wsBl);
    hipLaunchKernelGGL((net_kernel<1>), dim3(NBT), dim3(64), 0, stream,
                       x, y, We, be, Wd, bd, Wds, bds, wsBh, wsBl, out);
  } else {
    hipLaunchKernelGGL((net_kernel<0>), dim3(NBT), dim3(64), 0, stream,
                       x, y, We, be, Wd, bd, Wds, bds, wsBh, wsBl, out);
  }
}

// Round 9
// 943.151 us; speedup vs baseline: 1.2313x; 1.2313x over previous
//
#include <hip/hip_runtime.h>
#include <math.h>

// Problem constants (B=8, T=256 -> 2048 independent (b,t) pipelines)
// Structure: ONE WAVE (64 threads) per pipeline; no inter-wave barriers.
// R9 = R8 structure (pairwise B loads, acc[2][8], it-loop not unrolled) with
// __launch_bounds__(64,2): R8 proved the structure doesn't spill; (64,2)
// restores the grid-capped 2 waves/SIMD residency that (64,1) gave away.
#define NBT 2048

typedef __attribute__((ext_vector_type(8))) short short8;     // 8 bf16 (4 VGPRs)
typedef __attribute__((ext_vector_type(4))) float floatx4;    // MFMA C/D

struct SM {
  alignas(16) float xp[240];      // zero-padded encoder input (nonzero in [80,160))
  alignas(16) unsigned xhl[256];  // packed bf16: hi | lo<<16, zero-padded to 256
  alignas(16) float hsq[256];     // h^2 for top-64 ranking
  alignas(16) float yres[80];
  alignas(16) float beL[256];     // encoder bias staged in LDS
  alignas(16) float spad[240];    // padded buffer for sim windows
  alignas(16) float dval[64];     // compacted selected hidden values (ascending idx)
  alignas(16) int   dlist[64];    // compacted selected hidden indices (ascending)
  float xres[80];
  float yal[80];
  float xele[80];
  float decsrc[80];
  float zb[80];
  float energy[96];               // 81 valid + pad (6 m-tiles of 16)
  float mp_self[256];
  float mp_src[256];
  float ext[160];
  unsigned char smask[80];
  int smask_t;
};

// ---- wave-level primitives (64 lanes, butterfly -> all lanes hold result) ----
__device__ __forceinline__ float waveSum(float v){
  #pragma unroll
  for (int off = 32; off > 0; off >>= 1) v += __shfl_xor(v, off, 64);
  return v;
}
__device__ __forceinline__ int waveSumI(int v){
  #pragma unroll
  for (int off = 32; off > 0; off >>= 1) v += __shfl_xor(v, off, 64);
  return v;
}
__device__ __forceinline__ float waveMax(float v){
  #pragma unroll
  for (int off = 32; off > 0; off >>= 1) v = fmaxf(v, __shfl_xor(v, off, 64));
  return v;
}
// argmax with JAX tie rule: first (lowest index) max wins; symmetric butterfly
__device__ __forceinline__ int waveArgMax(float v, int idx){
  #pragma unroll
  for (int off = 32; off > 0; off >>= 1){
    float ov = __shfl_xor(v,   off, 64);
    int   oi = __shfl_xor(idx, off, 64);
    if (ov > v || (ov == v && oi < idx)){ v = ov; idx = oi; }
  }
  return idx;
}

// top-64 membership via rank for this lane's 4 hidden units (j = lane + 64q).
// rank = #{i: v_i > v_j} + #{i<j: v_i == v_j}; selected iff rank < 64.
// hsq[i4] reads are wave-uniform -> LDS broadcast, conflict-free.
__device__ __forceinline__ void rankTop64w(SM& sm, const float vsq[4], int lane, int sel[4]){
  int cnt[4] = {0,0,0,0};
  const float4* q4 = (const float4*)sm.hsq;
  #pragma unroll 4
  for (int i4 = 0; i4 < 64; i4++){
    float4 o = q4[i4];
    int ib = i4 * 4;
    #pragma unroll
    for (int q = 0; q < 4; q++){
      int j = lane + 64 * q;
      cnt[q] += (o.x > vsq[q] || (o.x == vsq[q] && (ib + 0) < j)) ? 1 : 0;
      cnt[q] += (o.y > vsq[q] || (o.y == vsq[q] && (ib + 1) < j)) ? 1 : 0;
      cnt[q] += (o.z > vsq[q] || (o.z == vsq[q] && (ib + 2) < j)) ? 1 : 0;
      cnt[q] += (o.w > vsq[q] || (o.w == vsq[q] && (ib + 3) < j)) ? 1 : 0;
    }
  }
  #pragma unroll
  for (int q = 0; q < 4; q++) sel[q] = (cnt[q] < 64) ? 1 : 0;
}

// Compact the exactly-64 selected (index,value) pairs into ascending-index LDS
// lists via wave ballots. Ascending order => decode accumulation order matches
// the reference (skipped entries are exact zeros: fmaf(0,w,a)==a bit-exactly).
__device__ __forceinline__ void compactSel(SM& sm, const int sel[4], const float val[4], int lane){
  unsigned long long mq[4];
  #pragma unroll
  for (int q = 0; q < 4; q++) mq[q] = __ballot(sel[q] != 0);
  int base1 = __popcll(mq[0]);
  int base2 = base1 + __popcll(mq[1]);
  int base3 = base2 + __popcll(mq[2]);
  int base[4] = {0, base1, base2, base3};
  unsigned long long below = (lane == 0) ? 0ull : ((~0ull) >> (64 - lane));
  #pragma unroll
  for (int q = 0; q < 4; q++){
    if (sel[q]){
      int pos = base[q] + (int)__popcll(mq[q] & below);
      sm.dlist[pos] = lane + 64 * q;
      sm.dval[pos]  = val[q];
    }
  }
}

// sim_argmax: cosine sim over 159 shifts of src vs yres; each lane owns shifts
// {lane, lane+64, lane+128}. Per-candidate fmaf chain order preserved.
__device__ __forceinline__ int simArgmax(SM& sm, const float* src, float* yal_out){
  int lane = threadIdx.x;
  __syncthreads();
  for (int i = lane; i < 240; i += 64)
    sm.spad[i] = (i >= 79 && i < 159) ? src[i - 79] : 0.f;
  __syncthreads();
  float yv2 = 0.f;
  for (int w = lane; w < 80; w += 64){ float yv = sm.yres[w]; yv2 = fmaf(yv, yv, yv2); }
  float nys = sqrtf(waveSum(yv2));

  int   sidx[3]; int svalid[3];
  #pragma unroll
  for (int c = 0; c < 3; c++){
    int s = lane + 64 * c;
    svalid[c] = (s < 159);
    sidx[c] = svalid[c] ? s : 0;      // clamp to keep reads in-bounds
  }
  float num[3] = {0.f,0.f,0.f}, nx[3] = {0.f,0.f,0.f};
  const float4* y4p = (const float4*)sm.yres;
  for (int w4 = 0; w4 < 20; w4++){
    float4 yy = y4p[w4];
    int w = w4 * 4;
    #pragma unroll
    for (int c = 0; c < 3; c++){
      float xa0 = sm.spad[sidx[c] + w + 0];
      float xa1 = sm.spad[sidx[c] + w + 1];
      float xa2 = sm.spad[sidx[c] + w + 2];
      float xa3 = sm.spad[sidx[c] + w + 3];
      num[c] = fmaf(xa0, yy.x, num[c]); nx[c] = fmaf(xa0, xa0, nx[c]);
      num[c] = fmaf(xa1, yy.y, num[c]); nx[c] = fmaf(xa1, xa1, nx[c]);
      num[c] = fmaf(xa2, yy.z, num[c]); nx[c] = fmaf(xa2, xa2, nx[c]);
      num[c] = fmaf(xa3, yy.w, num[c]); nx[c] = fmaf(xa3, xa3, nx[c]);
    }
  }
  float bv = -INFINITY; int bi = 0;
  #pragma unroll
  for (int c = 0; c < 3; c++){          // ascending index: strict > keeps lowest idx on ties
    if (svalid[c]){
      float simv = num[c] / (sqrtf(nx[c]) * nys + 1e-6f);
      if (simv > bv){ bv = simv; bi = lane + 64 * c; }
    }
  }
  int th = waveArgMax(bv, bi);
  for (int i = lane; i < 80; i += 64) yal_out[i] = sm.spad[th + i];
  __syncthreads();
  return th;
}

// One branch: MFMA energy (split bf16, kt-trimmed to nonzero support — bit-safe),
// argmax, exact fp32 row recompute, hsr, sparse decode, masked loss.
template<int USE_WS>
__device__ __forceinline__ void branchCompute(
    SM& sm, const float* __restrict__ We,
    const short8* __restrict__ wsBh, const short8* __restrict__ wsBl,
    const float* __restrict__ Wdec, const float* __restrict__ bdec,
    const float* enc_in, float* mask, const float* target,
    float* dec_out, int theta, bool first, float& lossAcc)
{
  int lane = threadIdx.x;
  int quad = lane >> 4, l15 = lane & 15;
  __syncthreads();
  for (int i = lane; i < 256; i += 64){
    float v = (i >= 80 && i < 160) ? enc_in[i - 80] : 0.f;
    if (i < 240) sm.xp[i] = v;
    unsigned bits = __float_as_uint(v);
    unsigned hi = bits >> 16;
    float hif = __uint_as_float(hi << 16);
    unsigned lo = __float_as_uint(v - hif) >> 16;
    sm.xhl[i] = hi | (lo << 16);
  }
  __syncthreads();

  const floatx4 zero4 = {0.f, 0.f, 0.f, 0.f};

  #pragma unroll 1
  for (int mh = 0; mh < 3; mh++){        // 3 m-passes x 2 m-tiles
    int ktlo = (mh == 0) ? 1 : 0;        // nonzero-support kt range for these m rows
    int kthi = 5 - mh;
    #pragma unroll 1
    for (int ng = 0; ng < 2; ng++){      // 2 n-passes x 8 n-tiles; acc[2][8]=64 regs
      floatx4 acc[2][8];
      #pragma unroll
      for (int m2 = 0; m2 < 2; m2++)
        #pragma unroll
        for (int nt = 0; nt < 8; nt++) acc[m2][nt] = zero4;

      #pragma unroll
      for (int kt = 0; kt < 5; kt++){
        if (kt < ktlo || kt >= kthi) continue;   // wave-uniform scalar skip; removed
                                                 // products are exactly 0 -> bit-safe
        // A fragments for this kt (built once per (ng,kt))
        short8 Ah[2], Al[2];
        #pragma unroll
        for (int m2 = 0; m2 < 2; m2++){
          int mt = mh * 2 + m2;
          int base = mt * 16 + l15 + kt * 32 + quad * 8;
          short8 ah, al;
          #pragma unroll
          for (int j = 0; j < 8; j++){
            unsigned u = sm.xhl[base + j];
            ah[j] = (short)(u & 0xffffu);
            al[j] = (short)(u >> 16);
          }
          Ah[m2] = ah; Al[m2] = al;
        }
        // B tiles pairwise: only 2 (hi,lo) tile pairs live at once (16 VGPRs)
        #pragma unroll
        for (int ntp = 0; ntp < 4; ntp++){
          short8 Bh0, Bl0, Bh1, Bl1;
          int nt0 = ng * 8 + ntp * 2;
          if (USE_WS){
            int t0 = (kt * 16 + nt0) * 64 + lane;
            Bh0 = wsBh[t0];       Bl0 = wsBl[t0];
            Bh1 = wsBh[t0 + 64];  Bl1 = wsBl[t0 + 64];
          } else {
            int k0 = kt * 32 + quad * 8;
            #pragma unroll
            for (int half = 0; half < 2; half++){
              short8 bh, bl;
              int n = (nt0 + half) * 16 + l15;
              #pragma unroll
              for (int j = 0; j < 8; j++){
                float v = We[(k0 + j) * 256 + n];
                unsigned bits = __float_as_uint(v);
                unsigned hi = bits >> 16;
                float hif = __uint_as_float(hi << 16);
                unsigned lo = __float_as_uint(v - hif) >> 16;
                bh[j] = (short)hi; bl[j] = (short)lo;
              }
              if (half == 0){ Bh0 = bh; Bl0 = bl; } else { Bh1 = bh; Bl1 = bl; }
            }
          }
          #pragma unroll
          for (int m2 = 0; m2 < 2; m2++){
            int a0 = ntp * 2, a1 = ntp * 2 + 1;
            acc[m2][a0] = __builtin_amdgcn_mfma_f32_16x16x32_bf16(Ah[m2], Bh0, acc[m2][a0], 0, 0, 0);
            acc[m2][a0] = __builtin_amdgcn_mfma_f32_16x16x32_bf16(Al[m2], Bh0, acc[m2][a0], 0, 0, 0);
            acc[m2][a0] = __builtin_amdgcn_mfma_f32_16x16x32_bf16(Ah[m2], Bl0, acc[m2][a0], 0, 0, 0);
            acc[m2][a1] = __builtin_amdgcn_mfma_f32_16x16x32_bf16(Ah[m2], Bh1, acc[m2][a1], 0, 0, 0);
            acc[m2][a1] = __builtin_amdgcn_mfma_f32_16x16x32_bf16(Al[m2], Bh1, acc[m2][a1], 0, 0, 0);
            acc[m2][a1] = __builtin_amdgcn_mfma_f32_16x16x32_bf16(Ah[m2], Bl1, acc[m2][a1], 0, 0, 0);
          }
        }
      }

      // epilogue: add bias, square, reduce over this pass's 128 columns (l15 butterfly)
      float bn[8];
      #pragma unroll
      for (int nt = 0; nt < 8; nt++) bn[nt] = sm.beL[(ng * 8 + nt) * 16 + l15];
      #pragma unroll
      for (int m2 = 0; m2 < 2; m2++){
        int mt = mh * 2 + m2;
        float er[4];
        #pragma unroll
        for (int r = 0; r < 4; r++){
          float s_ = 0.f;
          #pragma unroll
          for (int nt = 0; nt < 8; nt++){
            float hvv = acc[m2][nt][r] + bn[nt];
            s_ = fmaf(hvv, hvv, s_);
          }
          er[r] = s_;
        }
        #pragma unroll
        for (int x2 = 1; x2 < 16; x2 <<= 1){
          #pragma unroll
          for (int r = 0; r < 4; r++) er[r] += __shfl_xor(er[r], x2, 64);
        }
        if (l15 == 0){
          #pragma unroll
          for (int r = 0; r < 4; r++){
            int ei = mt * 16 + quad * 4 + r;
            sm.energy[ei] = (ng == 0) ? er[r] : (sm.energy[ei] + er[r]);
          }
        }
      }
      __syncthreads();   // waitcnt fence; pins pass boundaries (code-size/pressure guard)
    }
  }

  // argmax over 81 energies (padded rows >80 contain garbage correlations — mask them)
  float bv = sm.energy[lane]; int bi = lane;
  {
    int s2 = lane + 64;
    if (s2 < 81){
      float v2 = sm.energy[s2];
      if (v2 > bv){ bv = v2; bi = s2; }   // ascending index: ties keep lower
    }
  }
  int ind = waveArgMax(bv, bi);

  // recompute selected row h[ind, j] EXACTLY in fp32 for this lane's 4 js
  int roff = 80 - ind;
  float hv[4];
  #pragma unroll
  for (int q = 0; q < 4; q++) hv[q] = sm.beL[lane + 64 * q];
  #pragma unroll 4
  for (int w2 = 0; w2 < 80; w2++){
    float xv = sm.xp[80 + w2];
    const float* row = We + (w2 + roff) * 256;
    #pragma unroll
    for (int q = 0; q < 4; q++) hv[q] = fmaf(xv, row[lane + 64 * q], hv[q]);
  }

  // hsr (per lane's 4 js)
  float vsq[4];
  #pragma unroll
  for (int q = 0; q < 4; q++){ vsq[q] = hv[q] * hv[q]; sm.hsq[lane + 64 * q] = vsq[q]; }
  __syncthreads();
  int sel1[4];
  rankTop64w(sm, vsq, lane, sel1);
  float mpv[4];
  #pragma unroll
  for (int q = 0; q < 4; q++) mpv[q] = mask[lane + 64 * q];
  if (first){
    #pragma unroll
    for (int q = 0; q < 4; q++)
      mask[lane + 64 * q] = (float)sel1[q];
    compactSel(sm, sel1, hv, lane);
  } else {
    int st = sm.smask_t;
    float h2[4];
    #pragma unroll
    for (int q = 0; q < 4; q++){
      float interv = mpv[q] * (float)sel1[q];
      if (interv > 0.f && !st){
        float dd = hv[q] - (1.f - interv);
        lossAcc += dd * dd;
      }
      h2[q] = (mpv[q] > 0.f) ? 0.f : hv[q];
    }
    __syncthreads();               // rank1 readers done before hsq rewrite
    float vsq2[4];
    #pragma unroll
    for (int q = 0; q < 4; q++){ vsq2[q] = h2[q] * h2[q]; sm.hsq[lane + 64 * q] = vsq2[q]; }
    __syncthreads();
    int sel2[4];
    rankTop64w(sm, vsq2, lane, sel2);
    #pragma unroll
    for (int q = 0; q < 4; q++)
      mask[lane + 64 * q] = mpv[q] + (float)sel2[q];
    compactSel(sm, sel2, h2, lane);
  }
  __syncthreads();                 // compact list ready

  // sparse decode over the exactly-64 selected rows (ascending idx => bit-exact):
  // ext[d] = bdec[d] + sum_{sel h asc} val_h * Wdec[h*160+d]; lane owns d, d+64, d+128
  {
    int dc = 128 + (lane & 31);    // clamped third output (discarded for lane>=32)
    float a0 = bdec[lane], a1 = bdec[lane + 64], a2 = bdec[dc];
    #pragma unroll 8
    for (int i = 0; i < 64; i++){
      int idx = sm.dlist[i];       // wave-uniform broadcast
      float hval = sm.dval[i];
      const float* r = Wdec + idx * 160;
      a0 = fmaf(hval, r[lane], a0);
      a1 = fmaf(hval, r[lane + 64], a1);
      a2 = fmaf(hval, r[dc], a2);
    }
    sm.ext[lane] = a0;
    sm.ext[lane + 64] = a1;
    if (lane < 32) sm.ext[128 + lane] = a2;
  }
  __syncthreads();

  float mv = fabsf((float)(theta - 79));
  bool gate = (mv > 40.0f);        // ETH
  for (int d = lane; d < 80; d += 64){
    float dec = sm.ext[ind + d];
    dec_out[d] = dec;              // residual update uses decoded output regardless of gates
    float diff = dec - target[d];
    float l = (gate || sm.smask[d]) ? 0.f : diff * diff;
    lossAcc += l / (mv + 1.0f);
  }
  __syncthreads();
}

__global__ void __launch_bounds__(64) zero_out_kernel(float* out){
  if (threadIdx.x == 0) out[0] = 0.f;
}

// Pre-repack We into MFMA B-fragment layout (bf16 hi and lo), one 16B frag per lane per tile.
__global__ void __launch_bounds__(64) prep_we_kernel(
    const float* __restrict__ We, short8* __restrict__ bh, short8* __restrict__ bl){
  int tile = blockIdx.x;
  int lane = threadIdx.x;
  int kt = tile >> 4, nt = tile & 15;
  int k0 = kt * 32 + (lane >> 4) * 8;
  int n  = nt * 16 + (lane & 15);
  short8 h, l;
  #pragma unroll
  for (int j = 0; j < 8; j++){
    float v = We[(k0 + j) * 256 + n];
    unsigned bits = __float_as_uint(v);
    unsigned hi = bits >> 16;
    float hif = __uint_as_float(hi << 16);
    unsigned lo = __float_as_uint(v - hif) >> 16;
    h[j] = (short)hi; l[j] = (short)lo;
  }
  bh[tile * 64 + lane] = h;
  bl[tile * 64 + lane] = l;
}

template<int USE_WS>
__global__ void __launch_bounds__(64, 2) net_kernel(
    const float* __restrict__ x,  const float* __restrict__ y,
    const float* __restrict__ We, const float* __restrict__ be,
    const float* __restrict__ Wd, const float* __restrict__ bd,
    const float* __restrict__ Wds,const float* __restrict__ bds,
    const short8* __restrict__ wsBh, const short8* __restrict__ wsBl,
    float* out)
{
  __shared__ SM sm;
  int lane = threadIdx.x;
  int bt  = blockIdx.x;
  const float* xin = x + bt * 80;
  const float* yin = y + bt * 80;

  for (int i = lane; i < 80; i += 64){
    sm.xres[i] = xin[i];
    float yv = yin[i];
    sm.yres[i] = yv;
    sm.smask[i] = (yv == 0.f) ? 1 : 0;   // seq_mask from ORIGINAL y
  }
  for (int i = lane; i < 256; i += 64){
    sm.mp_self[i] = 0.f;
    sm.mp_src[i]  = 0.f;
    sm.beL[i] = be[i];
  }
  __syncthreads();
  {
    int c = 0;
    for (int i = lane; i < 80; i += 64) c += (int)sm.smask[i];
    int total = waveSumI(c);
    if (lane == 0) sm.smask_t = (total == 80) ? 1 : 0;
  }
  __syncthreads();

  float lossAcc = 0.f;

  #pragma unroll 1
  for (int it = 0; it < 4; it++){
    bool first = (it == 0);

    // --- align x_res to y_res ---
    int th1 = simArgmax(sm, sm.xres, sm.yal);

    // --- attention softmax(y_al * y_res) and z = y_al * attn ---
    {
      float p0 = sm.yal[lane] * sm.yres[lane];
      float p1 = (lane < 16) ? sm.yal[64 + lane] * sm.yres[64 + lane] : -INFINITY;
      float mx = waveMax(fmaxf(p0, p1));
      float e0 = expf(p0 - mx);
      float e1 = (lane < 16) ? expf(p1 - mx) : 0.f;
      float ssum = waveSum(e0 + e1);
      sm.zb[lane] = sm.yal[lane] * (e0 / ssum);
      if (lane < 16) sm.zb[64 + lane] = sm.yal[64 + lane] * (e1 / ssum);
    }
    __syncthreads();

    // --- reverse shift: x_ele[d] = z[d + 79 - theta] ---
    for (int d = lane; d < 80; d += 64){
      int q = d + 79 - th1;
      sm.xele[d] = (q >= 0 && q < 80) ? sm.zb[q] : 0.f;
    }

    // --- self branch ---
    branchCompute<USE_WS>(sm, We, wsBh, wsBl, Wds, bds,
                          sm.xele, sm.mp_self, sm.xres, sm.xele, th1, first, lossAcc);

    // --- re-align decoded x_ele to y_res ---
    int th2 = simArgmax(sm, sm.xele, sm.yal);

    // --- src branch ---
    branchCompute<USE_WS>(sm, We, wsBh, wsBl, Wd, bd,
                          sm.yal, sm.mp_src, sm.yres, sm.decsrc, th2, first, lossAcc);

    // --- residual updates ---
    __syncthreads();
    for (int d = lane; d < 80; d += 64){
      sm.xres[d] -= sm.xele[d];
      sm.yres[d] -= sm.decsrc[d];
    }
    __syncthreads();
  }

  float total = waveSum(lossAcc);
  if (lane == 0) atomicAdd(out, total * 0.25f);   // mean over 4 iterations
}

extern "C" void kernel_launch(void* const* d_in, const int* in_sizes, int n_in,
                              void* d_out, int out_size, void* d_ws, size_t ws_size,
                              hipStream_t stream) {
  const float* x   = (const float*)d_in[0];
  const float* y   = (const float*)d_in[1];
  const float* We  = (const float*)d_in[2];
  const float* be  = (const float*)d_in[3];
  const float* Wd  = (const float*)d_in[4];
  const float* bd  = (const float*)d_in[5];
  const float* Wds = (const float*)d_in[6];
  const float* bds = (const float*)d_in[7];
  float* out = (float*)d_out;

  // We-fragment repack buffers: 80 tiles x 64 lanes x 16B each for hi and lo
  const size_t fragCount = 80 * 64;                     // short8 elements per buffer
  const size_t fragBytes = fragCount * sizeof(short8);  // 81920 B
  int use_ws = (ws_size >= 2 * fragBytes) ? 1 : 0;
  short8* wsBh = (short8*)d_ws;
  short8* wsBl = wsBh + fragCount;

  hipLaunchKernelGGL(zero_out_kernel, dim3(1), dim3(64), 0, stream, out);
  if (use_ws){
    hipLaunchKernelGGL(prep_we_kernel, dim3(80), dim3(64), 0, stream, We, wsBh, wsBl);
    hipLaunchKernelGGL((net_kernel<1>), dim3(NBT), dim3(64), 0, stream,
                       x, y, We, be, Wd, bd, Wds, bds, wsBh, wsBl, out);
  } else {
    hipLaunchKernelGGL((net_kernel<0>), dim3(NBT), dim3(64), 0, stream,
                       x, y, We, be, Wd, bd, Wds, bds, wsBh, wsBl, out);
  }
}